// Round 7
// baseline (332.689 us; speedup 1.0000x reference)
//
#include <hip/hip_runtime.h>
#include <hip/hip_bf16.h>
#include <math.h>

typedef __bf16 bf16_t;
typedef bf16_t bf16x8 __attribute__((ext_vector_type(8)));
typedef float f32x4 __attribute__((ext_vector_type(4)));

#define BB 4
#define SS 2048
#define HH 16
#define DMODEL 1024
#define DHEAD 64
#define QSCALE 0.18033688011112042f   // 0.125 * log2(e): softmax via exp2

__device__ inline unsigned short f2bf(float f) {
    union { __hip_bfloat16 h; unsigned short u; } cvt;
    cvt.h = __float2bfloat16(f);
    return cvt.u;
}

// async global->LDS, 16B per lane. LDS dest = wave-uniform base + lane*16.
__device__ __forceinline__ void gll16(const unsigned short* g, unsigned short* l) {
    __builtin_amdgcn_global_load_lds(
        (const __attribute__((address_space(1))) unsigned int*)(g),
        (__attribute__((address_space(3))) unsigned int*)(l), 16, 0, 0);
}

// ---------------- weight pack (LDS-tiled transpose, both sides coalesced) ----------------
// bid<768: W_{Q,K,V}[h][m][d] -> qkvT[n=mat*1024+h*64+d][k=m]
// else:    W_O[h][dh][m]      -> woT [n=m][k=h*64+dh]
__global__ __launch_bounds__(256) void pack_w(
    const float* __restrict__ wq, const float* __restrict__ wk, const float* __restrict__ wv,
    const float* __restrict__ wo, unsigned short* __restrict__ qkvT, unsigned short* __restrict__ woT)
{
    __shared__ unsigned short tile[64 * 72];
    const int t = threadIdx.x;
    const int bid = blockIdx.x;
    const int r = t >> 2;
    const int c4 = (t & 3) * 16;
    if (bid < 768) {
        const int mat = bid >> 8;
        const int rem = bid & 255;
        const int h = rem >> 4;
        const int m0 = (rem & 15) * 64;
        const float* w = (mat == 0) ? wq : (mat == 1) ? wk : wv;
        const float* src = w + ((size_t)h << 16) + (size_t)(m0 + r) * 64 + c4;
#pragma unroll
        for (int k2 = 0; k2 < 4; k2++) {
            float4 v = *(const float4*)(src + k2 * 4);
            tile[(c4 + k2 * 4 + 0) * 72 + r] = f2bf(v.x);
            tile[(c4 + k2 * 4 + 1) * 72 + r] = f2bf(v.y);
            tile[(c4 + k2 * 4 + 2) * 72 + r] = f2bf(v.z);
            tile[(c4 + k2 * 4 + 3) * 72 + r] = f2bf(v.w);
        }
        __syncthreads();
        const int d = t >> 2;
        const int rq = (t & 3) * 16;
        unsigned short* dst = qkvT + (size_t)(mat * 1024 + h * 64 + d) * 1024 + m0 + rq;
        *(uint4*)(dst)     = *(const uint4*)(tile + d * 72 + rq);
        *(uint4*)(dst + 8) = *(const uint4*)(tile + d * 72 + rq + 8);
    } else {
        const int bid2 = bid - 768;
        const int h = bid2 >> 4;
        const int m0 = (bid2 & 15) * 64;
        const float* src = wo + ((size_t)h << 16) + (size_t)r * 1024 + m0 + c4;
#pragma unroll
        for (int k2 = 0; k2 < 4; k2++) {
            float4 v = *(const float4*)(src + k2 * 4);
            tile[(c4 + k2 * 4 + 0) * 72 + r] = f2bf(v.x);
            tile[(c4 + k2 * 4 + 1) * 72 + r] = f2bf(v.y);
            tile[(c4 + k2 * 4 + 2) * 72 + r] = f2bf(v.z);
            tile[(c4 + k2 * 4 + 3) * 72 + r] = f2bf(v.w);
        }
        __syncthreads();
        const int m = t >> 2;
        const int dq = (t & 3) * 16;
        unsigned short* dst = woT + (size_t)(m0 + m) * 1024 + h * 64 + dq;
        *(uint4*)(dst)     = *(const uint4*)(tile + m * 72 + dq);
        *(uint4*)(dst + 8) = *(const uint4*)(tile + m * 72 + dq + 8);
    }
}

// ---------------- GEMM 1: 128x128 tile; A staged from fp32 x (inline convert) ----------------
// qkv = x @ WqkvT^T + bias.  Q (pre-scaled by QSCALE), K -> [B,H,S,64] (swapped-operand
// MFMA, coalesced uint2 stores); V -> transposed [B,H,64,S].

__global__ __launch_bounds__(256) void gemm_qkv(
    const float* __restrict__ xg,             // [8192][1024] fp32
    const unsigned short* __restrict__ wT,    // [3072][1024] bf16
    const float* __restrict__ bq, const float* __restrict__ bk, const float* __restrict__ bv,
    unsigned short* __restrict__ qws, unsigned short* __restrict__ kws,
    unsigned short* __restrict__ vtw)         // [64][64][2048]
{
    __shared__ __align__(16) unsigned short lA[128 * 32];
    __shared__ __align__(16) unsigned short lB[128 * 32];
    const int t = threadIdx.x;
    const int lane = t & 63;
    const int w = t >> 6;
    const int quad = lane >> 4;
    const int l15 = lane & 15;
    const int bid = blockIdx.x;
    const int mb = (bid & 7) + ((bid / 192) << 3);   // same-m blocks share an XCD
    const int nb = (bid >> 3) % 24;
    const int n0 = nb * 128;
    const int m0 = mb * 128;
    const int wm = (w >> 1) * 64;
    const int wn = (w & 1) * 64;
    const int mat = n0 >> 10;

    f32x4 acc[4][4] = {};

    const int srow = w * 16 + (lane >> 2);
    const int scol = (lane & 3) * 8;
    const float* Ax0 = xg + (size_t)(m0 + srow) * 1024 + scol;
    const float* Ax1 = Ax0 + (size_t)64 * 1024;
    const unsigned short* Bg0 = wT + (size_t)(n0 + srow) * 1024 + scol;
    const unsigned short* Bg1 = Bg0 + (size_t)64 * 1024;
    unsigned short* lAd0 = lA + srow * 32 + scol;
    unsigned short* lAd1 = lA + (64 + srow) * 32 + scol;
    unsigned short* lB0 = lB + (w * 16) * 32;
    unsigned short* lB1 = lB + (64 + w * 16) * 32;

    for (int kt = 0; kt < 1024; kt += 32) {
        __syncthreads();
        {
            float4 u0 = *(const float4*)(Ax0 + kt);
            float4 u1 = *(const float4*)(Ax0 + kt + 4);
            float4 u2 = *(const float4*)(Ax1 + kt);
            float4 u3 = *(const float4*)(Ax1 + kt + 4);
            unsigned short p0[8] = { f2bf(u0.x), f2bf(u0.y), f2bf(u0.z), f2bf(u0.w),
                                     f2bf(u1.x), f2bf(u1.y), f2bf(u1.z), f2bf(u1.w) };
            unsigned short p1[8] = { f2bf(u2.x), f2bf(u2.y), f2bf(u2.z), f2bf(u2.w),
                                     f2bf(u3.x), f2bf(u3.y), f2bf(u3.z), f2bf(u3.w) };
            *(uint4*)lAd0 = *(uint4*)p0;
            *(uint4*)lAd1 = *(uint4*)p1;
        }
        gll16(Bg0 + kt, lB0);
        gll16(Bg1 + kt, lB1);
        __syncthreads();
        bf16x8 af[4], bfr[4];
#pragma unroll
        for (int i = 0; i < 4; i++) {
            af[i]  = *(const bf16x8*)(lA + (wm + i * 16 + l15) * 32 + quad * 8);
            bfr[i] = *(const bf16x8*)(lB + (wn + i * 16 + l15) * 32 + quad * 8);
        }
        if (mat != 2) {
#pragma unroll
            for (int i = 0; i < 4; i++)
#pragma unroll
                for (int j = 0; j < 4; j++)
                    acc[i][j] = __builtin_amdgcn_mfma_f32_16x16x32_bf16(bfr[j], af[i], acc[i][j], 0, 0, 0);
        } else {
#pragma unroll
            for (int i = 0; i < 4; i++)
#pragma unroll
                for (int j = 0; j < 4; j++)
                    acc[i][j] = __builtin_amdgcn_mfma_f32_16x16x32_bf16(af[i], bfr[j], acc[i][j], 0, 0, 0);
        }
    }

    const int b = m0 >> 11;
    if (mat != 2) {
        // swapped D: lane holds 4 consecutive d at fixed s -> uint2 stores
        const float* bias_p = (mat == 0) ? bq : bk;
        unsigned short* dst = (mat == 0) ? qws : kws;
        const float qscale = (mat == 0) ? QSCALE : 1.0f;
#pragma unroll
        for (int j = 0; j < 4; j++) {
            const int noff = wn + j * 16 + quad * 4;
            const int hglob = ((n0 & 1023) >> 6) + (noff >> 6);
            const int dbase = noff & 63;
            const float4 bv4 = *(const float4*)(bias_p + hglob * 64 + dbase);
            const float bias_r[4] = { bv4.x, bv4.y, bv4.z, bv4.w };
#pragma unroll
            for (int i = 0; i < 4; i++) {
                const int s = (m0 & 2047) + wm + i * 16 + l15;
                unsigned short pk[4];
#pragma unroll
                for (int r = 0; r < 4; r++) pk[r] = f2bf((acc[i][j][r] + bias_r[r]) * qscale);
                *(uint2*)(dst + (size_t)((b * 16 + hglob) * 2048 + s) * 64 + dbase) = *(uint2*)pk;
            }
        }
    } else {
        // normal D: 4 consecutive s at fixed d -> uint2 into V^T
#pragma unroll
        for (int j = 0; j < 4; j++) {
            const int n1 = (n0 & 1023) + wn + j * 16 + l15;
            const int h = n1 >> 6, d = n1 & 63;
            const float bias = bv[h * 64 + d];
#pragma unroll
            for (int i = 0; i < 4; i++) {
                const int s0 = (m0 & 2047) + wm + i * 16 + quad * 4;
                unsigned short pk[4];
#pragma unroll
                for (int r = 0; r < 4; r++) pk[r] = f2bf(acc[i][j][r] + bias);
                *(uint2*)(vtw + ((size_t)(b * 16 + h) * 64 + d) * 2048 + s0) = *(uint2*)pk;
            }
        }
    }
}

// ---------------- attention (r4-measured structure): 64-key chunks, swapped PV ----------------

__global__ __launch_bounds__(256) void attn3(
    const unsigned short* __restrict__ qws,   // pre-scaled by QSCALE
    const unsigned short* __restrict__ kws,
    const unsigned short* __restrict__ vtw,   // [bh][64][2048]
    unsigned short* __restrict__ zb)          // [8192][1024], col = h*64+d
{
    __shared__ __align__(16) unsigned short Ks[64 * 72];
    __shared__ __align__(16) unsigned short Vs[64 * 72];    // [d][key]
    __shared__ __align__(16) unsigned short Ps[4 * 16 * 72];

    const int t = threadIdx.x;
    const int lane = t & 63;
    const int w = t >> 6;
    const int quad = lane >> 4;
    const int l15 = lane & 15;

    const int qt = 31 - (blockIdx.x >> 6);   // longest blocks first
    const int bh = blockIdx.x & 63;
    const int q0 = qt * 64;
    const int qbase = q0 + w * 16;
    const size_t base = (size_t)bh * SS * DHEAD;
    const unsigned short* Q = qws + base;
    const unsigned short* K = kws + base;
    const unsigned short* Vt = vtw + base;   // [64][2048]

    bf16x8 qf0 = *(const bf16x8*)(Q + (size_t)(qbase + l15) * 64 + quad * 8);
    bf16x8 qf1 = *(const bf16x8*)(Q + (size_t)(qbase + l15) * 64 + 32 + quad * 8);

    f32x4 o[4] = {};          // swapped PV: o[dt] rows = d, col = q (l15)
    float lsum[4] = {0.f, 0.f, 0.f, 0.f};
    unsigned short* Pw = Ps + w * 16 * 72;

    const int sr = t >> 2;
    const int sc = (t & 3) * 8;
    const int nch = qt + 1;

    for (int c = 0; c < nch; c++) {
        const int kb = c * 64;
        __syncthreads();
        {
            const unsigned short* kp = K + (size_t)(kb + sr) * 64 + sc;
            *(uint4*)(Ks + sr * 72 + sc)      = *(const uint4*)(kp);
            *(uint4*)(Ks + sr * 72 + sc + 32) = *(const uint4*)(kp + 32);
            const unsigned short* vp = Vt + (size_t)sr * 2048 + kb + sc;
            *(uint4*)(Vs + sr * 72 + sc)      = *(const uint4*)(vp);
            *(uint4*)(Vs + sr * 72 + sc + 32) = *(const uint4*)(vp + 32);
        }
        __syncthreads();

        // scores: 8 MFMA (D: row=q quad*4+r, col=key l15)
        f32x4 s[4];
#pragma unroll
        for (int sub = 0; sub < 4; sub++) {
            bf16x8 kf0 = *(const bf16x8*)(Ks + (sub * 16 + l15) * 72 + quad * 8);
            bf16x8 kf1 = *(const bf16x8*)(Ks + (sub * 16 + l15) * 72 + 32 + quad * 8);
            f32x4 sv = {};
            sv = __builtin_amdgcn_mfma_f32_16x16x32_bf16(qf0, kf0, sv, 0, 0, 0);
            sv = __builtin_amdgcn_mfma_f32_16x16x32_bf16(qf1, kf1, sv, 0, 0, 0);
            s[sub] = sv;
        }

        // fixed-max softmax in exp2 domain (scores*log2e pre-folded into Q)
        if (c == nch - 1) {
            const int qg = qbase + quad * 4;
#pragma unroll
            for (int sub = 0; sub < 4; sub++) {
                const int key = kb + sub * 16 + l15;
#pragma unroll
                for (int r = 0; r < 4; r++) {
                    float p = (key > qg + r) ? 0.f : exp2f(s[sub][r]);
                    lsum[r] += p;
                    Pw[(quad * 4 + r) * 72 + sub * 16 + l15] = f2bf(p);
                }
            }
        } else {
#pragma unroll
            for (int sub = 0; sub < 4; sub++)
#pragma unroll
                for (int r = 0; r < 4; r++) {
                    float p = exp2f(s[sub][r]);
                    lsum[r] += p;
                    Pw[(quad * 4 + r) * 72 + sub * 16 + l15] = f2bf(p);
                }
        }
        // wave-private D-layout -> fragment-layout round trip
        asm volatile("s_waitcnt lgkmcnt(0)" ::: "memory");
        bf16x8 pf0 = *(const bf16x8*)(Pw + l15 * 72 + quad * 8);
        bf16x8 pf1 = *(const bf16x8*)(Pw + l15 * 72 + 32 + quad * 8);
#pragma unroll
        for (int dt = 0; dt < 4; dt++) {
            bf16x8 vf0 = *(const bf16x8*)(Vs + (dt * 16 + l15) * 72 + quad * 8);
            bf16x8 vf1 = *(const bf16x8*)(Vs + (dt * 16 + l15) * 72 + 32 + quad * 8);
            o[dt] = __builtin_amdgcn_mfma_f32_16x16x32_bf16(vf0, pf0, o[dt], 0, 0, 0);
            o[dt] = __builtin_amdgcn_mfma_f32_16x16x32_bf16(vf1, pf1, o[dt], 0, 0, 0);
        }
    }

    // row sums + redistribute (lane needs 1/sum for q = l15)
#pragma unroll
    for (int r = 0; r < 4; r++) {
        float v = lsum[r];
        v += __shfl_xor(v, 1);
        v += __shfl_xor(v, 2);
        v += __shfl_xor(v, 4);
        v += __shfl_xor(v, 8);
        lsum[r] = v;
    }
    const int srcl = (l15 >> 2) << 4;
    float t0 = __shfl(lsum[0], srcl);
    float t1 = __shfl(lsum[1], srcl);
    float t2 = __shfl(lsum[2], srcl);
    float t3 = __shfl(lsum[3], srcl);
    const int rr = l15 & 3;
    float den = (rr == 0) ? t0 : (rr == 1) ? t1 : (rr == 2) ? t2 : t3;
    const float inv = 1.0f / den;

    const int b = bh >> 4, h = bh & 15;
    const int q = qbase + l15;
    unsigned short* zrow = zb + (size_t)(b * 2048 + q) * 1024 + h * 64 + quad * 4;
#pragma unroll
    for (int dt = 0; dt < 4; dt++) {
        unsigned short pk[4];
#pragma unroll
        for (int r = 0; r < 4; r++) pk[r] = f2bf(o[dt][r] * inv);
        *(uint2*)(zrow + dt * 16) = *(uint2*)pk;
    }
}

// ---------------- GEMM 2: 64x128 tile (4 blocks/CU), swapped operands ----------------

__global__ __launch_bounds__(256) void gemm_out(
    const unsigned short* __restrict__ zb,    // [8192][1024]
    const unsigned short* __restrict__ wT,    // [1024][1024]
    const float* __restrict__ bo,
    float* __restrict__ out)
{
    __shared__ __align__(16) unsigned short lA[64 * 32];
    __shared__ __align__(16) unsigned short lB[128 * 32];
    const int t = threadIdx.x;
    const int lane = t & 63;
    const int w = t >> 6;
    const int quad = lane >> 4;
    const int l15 = lane & 15;
    const int bid = blockIdx.x;
    const int mb = (bid & 7) + ((bid >> 6) << 3);    // same-m blocks share an XCD
    const int nb = (bid >> 3) & 7;
    const int n0 = nb * 128;
    const int m0 = mb * 64;
    const int wm = (w >> 1) * 32;
    const int wn = (w & 1) * 64;

    f32x4 acc[2][4] = {};

    const int srow = w * 16 + (lane >> 2);
    const int scol = (lane & 3) * 8;
    const unsigned short* Ag0 = zb + (size_t)(m0 + srow) * 1024 + scol;
    const unsigned short* Bg0 = wT + (size_t)(n0 + srow) * 1024 + scol;
    const unsigned short* Bg1 = Bg0 + (size_t)64 * 1024;
    unsigned short* lA0 = lA + (w * 16) * 32;
    unsigned short* lB0 = lB + (w * 16) * 32;
    unsigned short* lB1 = lB + (64 + w * 16) * 32;

    for (int kt = 0; kt < 1024; kt += 32) {
        __syncthreads();
        gll16(Ag0 + kt, lA0);
        gll16(Bg0 + kt, lB0);
        gll16(Bg1 + kt, lB1);
        __syncthreads();
        bf16x8 af[2], bfr[4];
#pragma unroll
        for (int i = 0; i < 2; i++)
            af[i]  = *(const bf16x8*)(lA + (wm + i * 16 + l15) * 32 + quad * 8);
#pragma unroll
        for (int j = 0; j < 4; j++)
            bfr[j] = *(const bf16x8*)(lB + (wn + j * 16 + l15) * 32 + quad * 8);
#pragma unroll
        for (int i = 0; i < 2; i++)
#pragma unroll
            for (int j = 0; j < 4; j++)
                acc[i][j] = __builtin_amdgcn_mfma_f32_16x16x32_bf16(bfr[j], af[i], acc[i][j], 0, 0, 0);
    }

    // swapped D: lane holds 4 consecutive n at fixed s -> float4 stores
#pragma unroll
    for (int j = 0; j < 4; j++) {
        const int nbase = n0 + wn + j * 16 + quad * 4;
        const float4 bv4 = *(const float4*)(bo + nbase);
#pragma unroll
        for (int i = 0; i < 2; i++) {
            const int s = m0 + wm + i * 16 + l15;
            float4 v;
            v.x = acc[i][j][0] + bv4.x;
            v.y = acc[i][j][1] + bv4.y;
            v.z = acc[i][j][2] + bv4.z;
            v.w = acc[i][j][3] + bv4.w;
            *(float4*)(out + (size_t)s * 1024 + nbase) = v;
        }
    }
}

// ---------------- launch ----------------

extern "C" void kernel_launch(void* const* d_in, const int* in_sizes, int n_in,
                              void* d_out, int out_size, void* d_ws, size_t ws_size,
                              hipStream_t stream) {
    const float* x  = (const float*)d_in[0];
    const float* WQ = (const float*)d_in[1];
    const float* WK = (const float*)d_in[2];
    const float* WV = (const float*)d_in[3];
    const float* WO = (const float*)d_in[4];
    const float* bQ = (const float*)d_in[5];
    const float* bK = (const float*)d_in[6];
    const float* bV = (const float*)d_in[7];
    const float* bO = (const float*)d_in[8];
    float* out = (float*)d_out;

    char* ws = (char*)d_ws;
    unsigned short* zbuf = (unsigned short*)ws;                   // 16 MB
    unsigned short* wqkv = (unsigned short*)(ws + (16u << 20));   // 6 MB
    unsigned short* woT  = (unsigned short*)(ws + (22u << 20));   // 2 MB
    unsigned short* qws  = (unsigned short*)(ws + (24u << 20));   // 16 MB
    unsigned short* kws  = (unsigned short*)(ws + (40u << 20));   // 16 MB
    unsigned short* vtw  = (unsigned short*)(ws + (56u << 20));   // 16 MB, [bh][64][2048]

    pack_w<<<1024, 256, 0, stream>>>(WQ, WK, WV, WO, wqkv, woT);
    gemm_qkv<<<1536, 256, 0, stream>>>(x, wqkv, bQ, bK, bV, qws, kws, vtw);
    attn3<<<2048, 256, 0, stream>>>(qws, kws, vtw, zbuf);
    gemm_out<<<1024, 256, 0, stream>>>(zbuf, woT, bO, out);
}

// Round 8
// 295.234 us; speedup vs baseline: 1.1269x; 1.1269x over previous
//
#include <hip/hip_runtime.h>
#include <hip/hip_bf16.h>
#include <math.h>

typedef __bf16 bf16_t;
typedef bf16_t bf16x8 __attribute__((ext_vector_type(8)));
typedef float f32x4 __attribute__((ext_vector_type(4)));

#define BB 4
#define SS 2048
#define HH 16
#define DMODEL 1024
#define DHEAD 64
#define QSCALE 0.18033688011112042f   // 0.125 * log2(e): softmax via exp2

__device__ inline unsigned short f2bf(float f) {
    union { __hip_bfloat16 h; unsigned short u; } cvt;
    cvt.h = __float2bfloat16(f);
    return cvt.u;
}

// async global->LDS, 16B per lane. LDS dest = wave-uniform base + lane*16.
__device__ __forceinline__ void gll16(const unsigned short* g, unsigned short* l) {
    __builtin_amdgcn_global_load_lds(
        (const __attribute__((address_space(1))) unsigned int*)(g),
        (__attribute__((address_space(3))) unsigned int*)(l), 16, 0, 0);
}

// ---------------- pack kernels ----------------

__global__ void pack_x(const float* __restrict__ x, unsigned short* __restrict__ xb) {
    int i = blockIdx.x * 256 + threadIdx.x;
    const float4 v = ((const float4*)x)[i];
    unsigned short o[4] = { f2bf(v.x), f2bf(v.y), f2bf(v.z), f2bf(v.w) };
    *(uint2*)(xb + 4 * (size_t)i) = *(uint2*)o;
}

// LDS-tiled transposing weight pack (both sides coalesced).
__global__ __launch_bounds__(256) void pack_w(
    const float* __restrict__ wq, const float* __restrict__ wk, const float* __restrict__ wv,
    const float* __restrict__ wo, unsigned short* __restrict__ qkvT, unsigned short* __restrict__ woT)
{
    __shared__ unsigned short tile[64 * 72];
    const int t = threadIdx.x;
    const int bid = blockIdx.x;
    const int r = t >> 2;
    const int c4 = (t & 3) * 16;
    if (bid < 768) {
        const int mat = bid >> 8;
        const int rem = bid & 255;
        const int h = rem >> 4;
        const int m0 = (rem & 15) * 64;
        const float* w = (mat == 0) ? wq : (mat == 1) ? wk : wv;
        const float* src = w + ((size_t)h << 16) + (size_t)(m0 + r) * 64 + c4;
#pragma unroll
        for (int k2 = 0; k2 < 4; k2++) {
            float4 v = *(const float4*)(src + k2 * 4);
            tile[(c4 + k2 * 4 + 0) * 72 + r] = f2bf(v.x);
            tile[(c4 + k2 * 4 + 1) * 72 + r] = f2bf(v.y);
            tile[(c4 + k2 * 4 + 2) * 72 + r] = f2bf(v.z);
            tile[(c4 + k2 * 4 + 3) * 72 + r] = f2bf(v.w);
        }
        __syncthreads();
        const int d = t >> 2;
        const int rq = (t & 3) * 16;
        unsigned short* dst = qkvT + (size_t)(mat * 1024 + h * 64 + d) * 1024 + m0 + rq;
        *(uint4*)(dst)     = *(const uint4*)(tile + d * 72 + rq);
        *(uint4*)(dst + 8) = *(const uint4*)(tile + d * 72 + rq + 8);
    } else {
        const int bid2 = bid - 768;
        const int h = bid2 >> 4;
        const int m0 = (bid2 & 15) * 64;
        const float* src = wo + ((size_t)h << 16) + (size_t)r * 1024 + m0 + c4;
#pragma unroll
        for (int k2 = 0; k2 < 4; k2++) {
            float4 v = *(const float4*)(src + k2 * 4);
            tile[(c4 + k2 * 4 + 0) * 72 + r] = f2bf(v.x);
            tile[(c4 + k2 * 4 + 1) * 72 + r] = f2bf(v.y);
            tile[(c4 + k2 * 4 + 2) * 72 + r] = f2bf(v.z);
            tile[(c4 + k2 * 4 + 3) * 72 + r] = f2bf(v.w);
        }
        __syncthreads();
        const int m = t >> 2;
        const int dq = (t & 3) * 16;
        unsigned short* dst = woT + (size_t)(m0 + m) * 1024 + h * 64 + dq;
        *(uint4*)(dst)     = *(const uint4*)(tile + m * 72 + dq);
        *(uint4*)(dst + 8) = *(const uint4*)(tile + m * 72 + dq + 8);
    }
}

// ---------------- GEMM 1: 128x128 tile, BK=64, all-gll16 staging ----------------
// qkv = xb @ WqkvT^T + bias.  Q (pre-scaled QSCALE), K -> [B,H,S,64] (swapped-operand
// MFMA, coalesced uint2 stores); V -> transposed [B,H,64,S].

__global__ __launch_bounds__(256) void gemm_qkv(
    const unsigned short* __restrict__ xb,    // [8192][1024] bf16
    const unsigned short* __restrict__ wT,    // [3072][1024] bf16
    const float* __restrict__ bq, const float* __restrict__ bk, const float* __restrict__ bv,
    unsigned short* __restrict__ qws, unsigned short* __restrict__ kws,
    unsigned short* __restrict__ vtw)         // [64][64][2048]
{
    __shared__ __align__(16) unsigned short lA[128 * 64];   // 16 KB
    __shared__ __align__(16) unsigned short lB[128 * 64];   // 16 KB
    const int t = threadIdx.x;
    const int lane = t & 63;
    const int w = t >> 6;
    const int quad = lane >> 4;
    const int l15 = lane & 15;
    const int bid = blockIdx.x;
    const int mb = (bid & 7) + ((bid / 192) << 3);   // same-m blocks share an XCD
    const int nb = (bid >> 3) % 24;
    const int n0 = nb * 128;
    const int m0 = mb * 128;
    const int wm = (w >> 1) * 64;
    const int wn = (w & 1) * 64;
    const int mat = n0 >> 10;

    f32x4 acc[4][4] = {};

    // staging: wave w owns rows [w*32, w*32+32); call c covers 8 rows
    const int srow = lane >> 3;          // 0..7
    const int scol = (lane & 7) * 8;     // 0..56
    const unsigned short* Ag = xb + (size_t)(m0 + w * 32 + srow) * 1024 + scol;
    const unsigned short* Bg = wT + (size_t)(n0 + w * 32 + srow) * 1024 + scol;
    unsigned short* lAw = lA + (w * 32) * 64;
    unsigned short* lBw = lB + (w * 32) * 64;

    for (int kt = 0; kt < 1024; kt += 64) {
        __syncthreads();
#pragma unroll
        for (int c = 0; c < 4; c++) {
            gll16(Ag + (size_t)(c * 8) * 1024 + kt, lAw + c * 8 * 64);
            gll16(Bg + (size_t)(c * 8) * 1024 + kt, lBw + c * 8 * 64);
        }
        __syncthreads();
#pragma unroll
        for (int kk = 0; kk < 2; kk++) {
            bf16x8 af[4], bfr[4];
#pragma unroll
            for (int i = 0; i < 4; i++) {
                af[i]  = *(const bf16x8*)(lA + (wm + i * 16 + l15) * 64 + kk * 32 + quad * 8);
                bfr[i] = *(const bf16x8*)(lB + (wn + i * 16 + l15) * 64 + kk * 32 + quad * 8);
            }
            if (mat != 2) {
#pragma unroll
                for (int i = 0; i < 4; i++)
#pragma unroll
                    for (int j = 0; j < 4; j++)
                        acc[i][j] = __builtin_amdgcn_mfma_f32_16x16x32_bf16(bfr[j], af[i], acc[i][j], 0, 0, 0);
            } else {
#pragma unroll
                for (int i = 0; i < 4; i++)
#pragma unroll
                    for (int j = 0; j < 4; j++)
                        acc[i][j] = __builtin_amdgcn_mfma_f32_16x16x32_bf16(af[i], bfr[j], acc[i][j], 0, 0, 0);
            }
        }
    }

    const int b = m0 >> 11;
    if (mat != 2) {
        // swapped D: lane holds 4 consecutive d at fixed s -> uint2 stores
        const float* bias_p = (mat == 0) ? bq : bk;
        unsigned short* dst = (mat == 0) ? qws : kws;
        const float qscale = (mat == 0) ? QSCALE : 1.0f;
#pragma unroll
        for (int j = 0; j < 4; j++) {
            const int noff = wn + j * 16 + quad * 4;
            const int hglob = ((n0 & 1023) >> 6) + (noff >> 6);
            const int dbase = noff & 63;
            const float4 bv4 = *(const float4*)(bias_p + hglob * 64 + dbase);
            const float bias_r[4] = { bv4.x, bv4.y, bv4.z, bv4.w };
#pragma unroll
            for (int i = 0; i < 4; i++) {
                const int s = (m0 & 2047) + wm + i * 16 + l15;
                unsigned short pk[4];
#pragma unroll
                for (int r = 0; r < 4; r++) pk[r] = f2bf((acc[i][j][r] + bias_r[r]) * qscale);
                *(uint2*)(dst + (size_t)((b * 16 + hglob) * 2048 + s) * 64 + dbase) = *(uint2*)pk;
            }
        }
    } else {
        // normal D: 4 consecutive s at fixed d -> uint2 into V^T
#pragma unroll
        for (int j = 0; j < 4; j++) {
            const int n1 = (n0 & 1023) + wn + j * 16 + l15;
            const int h = n1 >> 6, d = n1 & 63;
            const float bias = bv[h * 64 + d];
#pragma unroll
            for (int i = 0; i < 4; i++) {
                const int s0 = (m0 & 2047) + wm + i * 16 + quad * 4;
                unsigned short pk[4];
#pragma unroll
                for (int r = 0; r < 4; r++) pk[r] = f2bf(acc[i][j][r] + bias);
                *(uint2*)(vtw + ((size_t)(b * 16 + h) * 64 + d) * 2048 + s0) = *(uint2*)pk;
            }
        }
    }
}

// ---------------- attention (r4-measured structure): 64-key chunks, swapped PV ----------------

__global__ __launch_bounds__(256) void attn3(
    const unsigned short* __restrict__ qws,   // pre-scaled by QSCALE
    const unsigned short* __restrict__ kws,
    const unsigned short* __restrict__ vtw,   // [bh][64][2048]
    unsigned short* __restrict__ zb)          // [8192][1024], col = h*64+d
{
    __shared__ __align__(16) unsigned short Ks[64 * 72];
    __shared__ __align__(16) unsigned short Vs[64 * 72];    // [d][key]
    __shared__ __align__(16) unsigned short Ps[4 * 16 * 72];

    const int t = threadIdx.x;
    const int lane = t & 63;
    const int w = t >> 6;
    const int quad = lane >> 4;
    const int l15 = lane & 15;

    const int qt = 31 - (blockIdx.x >> 6);   // longest blocks first
    const int bh = blockIdx.x & 63;
    const int q0 = qt * 64;
    const int qbase = q0 + w * 16;
    const size_t base = (size_t)bh * SS * DHEAD;
    const unsigned short* Q = qws + base;
    const unsigned short* K = kws + base;
    const unsigned short* Vt = vtw + base;   // [64][2048]

    bf16x8 qf0 = *(const bf16x8*)(Q + (size_t)(qbase + l15) * 64 + quad * 8);
    bf16x8 qf1 = *(const bf16x8*)(Q + (size_t)(qbase + l15) * 64 + 32 + quad * 8);

    f32x4 o[4] = {};          // swapped PV: o[dt] rows = d, col = q (l15)
    float lsum[4] = {0.f, 0.f, 0.f, 0.f};
    unsigned short* Pw = Ps + w * 16 * 72;

    const int sr = t >> 2;
    const int sc = (t & 3) * 8;
    const int nch = qt + 1;

    for (int c = 0; c < nch; c++) {
        const int kb = c * 64;
        __syncthreads();
        {
            const unsigned short* kp = K + (size_t)(kb + sr) * 64 + sc;
            *(uint4*)(Ks + sr * 72 + sc)      = *(const uint4*)(kp);
            *(uint4*)(Ks + sr * 72 + sc + 32) = *(const uint4*)(kp + 32);
            const unsigned short* vp = Vt + (size_t)sr * 2048 + kb + sc;
            *(uint4*)(Vs + sr * 72 + sc)      = *(const uint4*)(vp);
            *(uint4*)(Vs + sr * 72 + sc + 32) = *(const uint4*)(vp + 32);
        }
        __syncthreads();

        // scores: 8 MFMA (D: row=q quad*4+r, col=key l15)
        f32x4 s[4];
#pragma unroll
        for (int sub = 0; sub < 4; sub++) {
            bf16x8 kf0 = *(const bf16x8*)(Ks + (sub * 16 + l15) * 72 + quad * 8);
            bf16x8 kf1 = *(const bf16x8*)(Ks + (sub * 16 + l15) * 72 + 32 + quad * 8);
            f32x4 sv = {};
            sv = __builtin_amdgcn_mfma_f32_16x16x32_bf16(qf0, kf0, sv, 0, 0, 0);
            sv = __builtin_amdgcn_mfma_f32_16x16x32_bf16(qf1, kf1, sv, 0, 0, 0);
            s[sub] = sv;
        }

        // fixed-max softmax in exp2 domain; P stored as truncated bf16 (1 VALU op)
        if (c == nch - 1) {
            const int qg = qbase + quad * 4;
#pragma unroll
            for (int sub = 0; sub < 4; sub++) {
                const int key = kb + sub * 16 + l15;
#pragma unroll
                for (int r = 0; r < 4; r++) {
                    float p = (key > qg + r) ? 0.f : exp2f(s[sub][r]);
                    lsum[r] += p;
                    Pw[(quad * 4 + r) * 72 + sub * 16 + l15] =
                        (unsigned short)(__builtin_bit_cast(unsigned, p) >> 16);
                }
            }
        } else {
#pragma unroll
            for (int sub = 0; sub < 4; sub++)
#pragma unroll
                for (int r = 0; r < 4; r++) {
                    float p = exp2f(s[sub][r]);
                    lsum[r] += p;
                    Pw[(quad * 4 + r) * 72 + sub * 16 + l15] =
                        (unsigned short)(__builtin_bit_cast(unsigned, p) >> 16);
                }
        }
        // wave-private D-layout -> fragment-layout round trip
        asm volatile("s_waitcnt lgkmcnt(0)" ::: "memory");
        bf16x8 pf0 = *(const bf16x8*)(Pw + l15 * 72 + quad * 8);
        bf16x8 pf1 = *(const bf16x8*)(Pw + l15 * 72 + 32 + quad * 8);
#pragma unroll
        for (int dt = 0; dt < 4; dt++) {
            bf16x8 vf0 = *(const bf16x8*)(Vs + (dt * 16 + l15) * 72 + quad * 8);
            bf16x8 vf1 = *(const bf16x8*)(Vs + (dt * 16 + l15) * 72 + 32 + quad * 8);
            o[dt] = __builtin_amdgcn_mfma_f32_16x16x32_bf16(vf0, pf0, o[dt], 0, 0, 0);
            o[dt] = __builtin_amdgcn_mfma_f32_16x16x32_bf16(vf1, pf1, o[dt], 0, 0, 0);
        }
    }

    // row sums + redistribute (lane needs 1/sum for q = l15)
#pragma unroll
    for (int r = 0; r < 4; r++) {
        float v = lsum[r];
        v += __shfl_xor(v, 1);
        v += __shfl_xor(v, 2);
        v += __shfl_xor(v, 4);
        v += __shfl_xor(v, 8);
        lsum[r] = v;
    }
    const int srcl = (l15 >> 2) << 4;
    float t0 = __shfl(lsum[0], srcl);
    float t1 = __shfl(lsum[1], srcl);
    float t2 = __shfl(lsum[2], srcl);
    float t3 = __shfl(lsum[3], srcl);
    const int rr = l15 & 3;
    float den = (rr == 0) ? t0 : (rr == 1) ? t1 : (rr == 2) ? t2 : t3;
    const float inv = 1.0f / den;

    const int b = bh >> 4, h = bh & 15;
    const int q = qbase + l15;
    unsigned short* zrow = zb + (size_t)(b * 2048 + q) * 1024 + h * 64 + quad * 4;
#pragma unroll
    for (int dt = 0; dt < 4; dt++) {
        unsigned short pk[4];
#pragma unroll
        for (int r = 0; r < 4; r++) pk[r] = f2bf(o[dt][r] * inv);
        *(uint2*)(zrow + dt * 16) = *(uint2*)pk;
    }
}

// ---------------- GEMM 2: 64x128 tile, BK=64, swapped operands ----------------

__global__ __launch_bounds__(256) void gemm_out(
    const unsigned short* __restrict__ zb,    // [8192][1024]
    const unsigned short* __restrict__ wT,    // [1024][1024]
    const float* __restrict__ bo,
    float* __restrict__ out)
{
    __shared__ __align__(16) unsigned short lA[64 * 64];    // 8 KB
    __shared__ __align__(16) unsigned short lB[128 * 64];   // 16 KB
    const int t = threadIdx.x;
    const int lane = t & 63;
    const int w = t >> 6;
    const int quad = lane >> 4;
    const int l15 = lane & 15;
    const int bid = blockIdx.x;
    const int mb = (bid & 7) + ((bid >> 6) << 3);    // same-m blocks share an XCD
    const int nb = (bid >> 3) & 7;
    const int n0 = nb * 128;
    const int m0 = mb * 64;
    const int wm = (w >> 1) * 32;
    const int wn = (w & 1) * 64;

    f32x4 acc[2][4] = {};

    const int srow = lane >> 3;
    const int scol = (lane & 7) * 8;
    const unsigned short* Ag = zb + (size_t)(m0 + w * 16 + srow) * 1024 + scol;
    const unsigned short* Bg = wT + (size_t)(n0 + w * 32 + srow) * 1024 + scol;
    unsigned short* lAw = lA + (w * 16) * 64;
    unsigned short* lBw = lB + (w * 32) * 64;

    for (int kt = 0; kt < 1024; kt += 64) {
        __syncthreads();
#pragma unroll
        for (int c = 0; c < 2; c++)
            gll16(Ag + (size_t)(c * 8) * 1024 + kt, lAw + c * 8 * 64);
#pragma unroll
        for (int c = 0; c < 4; c++)
            gll16(Bg + (size_t)(c * 8) * 1024 + kt, lBw + c * 8 * 64);
        __syncthreads();
#pragma unroll
        for (int kk = 0; kk < 2; kk++) {
            bf16x8 af[2], bfr[4];
#pragma unroll
            for (int i = 0; i < 2; i++)
                af[i]  = *(const bf16x8*)(lA + (wm + i * 16 + l15) * 64 + kk * 32 + quad * 8);
#pragma unroll
            for (int j = 0; j < 4; j++)
                bfr[j] = *(const bf16x8*)(lB + (wn + j * 16 + l15) * 64 + kk * 32 + quad * 8);
#pragma unroll
            for (int i = 0; i < 2; i++)
#pragma unroll
                for (int j = 0; j < 4; j++)
                    acc[i][j] = __builtin_amdgcn_mfma_f32_16x16x32_bf16(bfr[j], af[i], acc[i][j], 0, 0, 0);
        }
    }

    // swapped D: lane holds 4 consecutive n at fixed s -> float4 stores
#pragma unroll
    for (int j = 0; j < 4; j++) {
        const int nbase = n0 + wn + j * 16 + quad * 4;
        const float4 bv4 = *(const float4*)(bo + nbase);
#pragma unroll
        for (int i = 0; i < 2; i++) {
            const int s = m0 + wm + i * 16 + l15;
            float4 v;
            v.x = acc[i][j][0] + bv4.x;
            v.y = acc[i][j][1] + bv4.y;
            v.z = acc[i][j][2] + bv4.z;
            v.w = acc[i][j][3] + bv4.w;
            *(float4*)(out + (size_t)s * 1024 + nbase) = v;
        }
    }
}

// ---------------- launch ----------------

extern "C" void kernel_launch(void* const* d_in, const int* in_sizes, int n_in,
                              void* d_out, int out_size, void* d_ws, size_t ws_size,
                              hipStream_t stream) {
    const float* x  = (const float*)d_in[0];
    const float* WQ = (const float*)d_in[1];
    const float* WK = (const float*)d_in[2];
    const float* WV = (const float*)d_in[3];
    const float* WO = (const float*)d_in[4];
    const float* bQ = (const float*)d_in[5];
    const float* bK = (const float*)d_in[6];
    const float* bV = (const float*)d_in[7];
    const float* bO = (const float*)d_in[8];
    float* out = (float*)d_out;

    char* ws = (char*)d_ws;
    unsigned short* xb   = (unsigned short*)ws;                   // 16 MB (reused as zbuf)
    unsigned short* wqkv = (unsigned short*)(ws + (16u << 20));   // 6 MB
    unsigned short* woT  = (unsigned short*)(ws + (22u << 20));   // 2 MB
    unsigned short* qws  = (unsigned short*)(ws + (24u << 20));   // 16 MB
    unsigned short* kws  = (unsigned short*)(ws + (40u << 20));   // 16 MB
    unsigned short* vtw  = (unsigned short*)(ws + (56u << 20));   // 16 MB, [bh][64][2048]
    unsigned short* zbuf = xb;                                    // x dead after gemm_qkv

    pack_x<<<8192, 256, 0, stream>>>(x, xb);
    pack_w<<<1024, 256, 0, stream>>>(WQ, WK, WV, WO, wqkv, woT);
    gemm_qkv<<<1536, 256, 0, stream>>>(xb, wqkv, bQ, bK, bV, qws, kws, vtw);
    attn3<<<2048, 256, 0, stream>>>(qws, kws, vtw, zbuf);
    gemm_out<<<1024, 256, 0, stream>>>(zbuf, woT, bO, out);
}